// Round 1
// baseline (1323.050 us; speedup 1.0000x reference)
//
#include <hip/hip_runtime.h>
#include <stdint.h>

// ---- problem constants ----
#define NBG   64      // graphs
#define NPER  32      // nodes per graph
#define DNODE 320
#define FEAT  1472
#define HIDN  2944
#define FEATP 1536    // FEAT padded to x128 for layer-2 N
#define NA    11
#define NROWS 2048    // NBG*NPER
#define MEDGE 65536   // NBG*NPER*NPER

typedef __attribute__((ext_vector_type(8))) short    bf16x8;
typedef __attribute__((ext_vector_type(4))) float    fv4;
typedef __attribute__((ext_vector_type(4))) unsigned uiv4;

__device__ __forceinline__ unsigned short f2bf(float f) {
  unsigned u = __builtin_bit_cast(unsigned, f);
  u += 0x7fffu + ((u >> 16) & 1u);
  return (unsigned short)(u >> 16);
}
__device__ __forceinline__ float bf2f(unsigned short h) {
  unsigned u = ((unsigned)h) << 16;
  return __builtin_bit_cast(float, u);
}
__device__ __forceinline__ unsigned cvt_pk_bf16(float lo, float hi) {
  unsigned r;
  asm("v_cvt_pk_bf16_f32 %0, %1, %2" : "=v"(r) : "v"(lo), "v"(hi));
  return r;
}
// async global->LDS, 16B per lane; lds base wave-uniform (HW adds lane*16)
__device__ __forceinline__ void gload_lds16(const void* g, void* l) {
  __builtin_amdgcn_global_load_lds((const __attribute__((address_space(1))) void*)g,
                                   (__attribute__((address_space(3))) void*)l, 16, 0, 0);
}

// ---- transpose f32 [K][N] -> bf16 [Npad][K]; rows n>=N zero-filled ----
__global__ void k_transpose_bf16(const float* __restrict__ src, unsigned short* __restrict__ dst,
                                 int K, int N, int Npad) {
  __shared__ float tile[64][65];
  int k0 = blockIdx.x * 64, n0 = blockIdx.y * 64;
  int r = threadIdx.x >> 2, cb = (threadIdx.x & 3) * 16;
  const float* srow = src + (size_t)(k0 + r) * N + n0 + cb;
#pragma unroll
  for (int c = 0; c < 16; ++c) {
    int n = n0 + cb + c;
    tile[r][cb + c] = (n < N) ? srow[c] : 0.f;
  }
  __syncthreads();
  unsigned short* drow = dst + (size_t)(n0 + r) * K + k0 + cb;
#pragma unroll
  for (int c = 0; c < 16; ++c) drow[c] = f2bf(tile[cb + c][r]);
}

// ---- embeddings -> xb bf16 [2048][320] ----
__global__ void k_embed(const int* __restrict__ idx, const int* __restrict__ mlt,
                        const float* __restrict__ id_emb, const float* __restrict__ mult_emb,
                        unsigned short* __restrict__ xb) {
  int t = blockIdx.x, c = threadIdx.x;
  int iv = idx[t], mv = mlt[t];
  xb[t * DNODE + c] = f2bf(id_emb[iv * 256 + c]);
  if (c < 64) xb[t * DNODE + 256 + c] = f2bf(mult_emb[mv * 64 + c]);
}

// ---- agg f32 [64][320] = mean over 32 nodes ----
__global__ void k_agg(const unsigned short* __restrict__ xb, float* __restrict__ agg) {
  int b = blockIdx.x;
  for (int d = threadIdx.x; d < DNODE; d += 256) {
    float s = 0.f;
    for (int i = 0; i < NPER; ++i) s += bf2f(xb[(b * NPER + i) * DNODE + d]);
    agg[b * DNODE + d] = s * (1.f / 32.f);
  }
}

// ---- za bf16 [128][832] = [z | agg], rows 64..127 zero ----
__global__ void k_za(const float* __restrict__ z, const float* __restrict__ agg,
                     unsigned short* __restrict__ za) {
  int b = blockIdx.x;
  for (int c = threadIdx.x; c < 832; c += 256) {
    unsigned short v = 0;
    if (b < NBG) v = (c < 512) ? f2bf(z[b * 512 + c]) : f2bf(agg[b * DNODE + (c - 512)]);
    za[b * 832 + c] = v;
  }
}

// ---- layer-1 GEMM: C[M][2944] (f32) = A(bf16,[M][sA] slice) @ W1T(bf16 [2944][1472])^T ----
__global__ void k_gemm1(const unsigned short* __restrict__ A, int sA, int Mrows,
                        const unsigned short* __restrict__ W1T, int kOff, int Ksteps,
                        float* __restrict__ C, const float* __restrict__ bias) {
  __shared__ alignas(16) unsigned short Als[128 * 32];
  __shared__ alignas(16) unsigned short Bls[128 * 32];
  int bx = blockIdx.x;
  int mt = bx / 23, nc = bx - mt * 23;
  int m0 = mt * 128, n0 = nc * 128;
  int tid = threadIdx.x, lane = tid & 63, w = tid >> 6;

  fv4 acc[4][4] = {};
  for (int kt = 0; kt < Ksteps; ++kt) {
    int k0 = kt * 32;
    __syncthreads();
#pragma unroll
    for (int q = 0; q < 2; ++q) {
      int seg = w * 2 + q;
      int row = seg * 16 + (lane >> 2);
      int col = (lane & 3) * 8;
      gload_lds16(A + (size_t)(m0 + row) * sA + k0 + col, &Als[seg * 512]);
      gload_lds16(W1T + (size_t)(n0 + row) * FEAT + kOff + k0 + col, &Bls[seg * 512]);
    }
    __syncthreads();
    bf16x8 aF[4], bF[4];
#pragma unroll
    for (int mf = 0; mf < 4; ++mf)
      aF[mf] = *(const bf16x8*)&Als[((w >> 1) * 64 + mf * 16 + (lane & 15)) * 32 + (lane >> 4) * 8];
#pragma unroll
    for (int nf = 0; nf < 4; ++nf)
      bF[nf] = *(const bf16x8*)&Bls[((w & 1) * 64 + nf * 16 + (lane & 15)) * 32 + (lane >> 4) * 8];
#pragma unroll
    for (int mf = 0; mf < 4; ++mf)
#pragma unroll
      for (int nf = 0; nf < 4; ++nf)
        acc[mf][nf] = __builtin_amdgcn_mfma_f32_16x16x32_bf16(aF[mf], bF[nf], acc[mf][nf], 0, 0, 0);
  }
  int mq = (w >> 1) * 64, nq = (w & 1) * 64;
#pragma unroll
  for (int mf = 0; mf < 4; ++mf)
#pragma unroll
    for (int nf = 0; nf < 4; ++nf) {
      int n = n0 + nq + nf * 16 + (lane & 15);
      float bv = bias ? bias[n] : 0.f;
#pragma unroll
      for (int r = 0; r < 4; ++r) {
        int m = m0 + mq + mf * 16 + (lane >> 4) * 4 + r;
        if (m < Mrows) C[(size_t)m * HIDN + n] = acc[mf][nf][r] + bv;
      }
    }
}

// ---- PQ1 = P1 + Q[b] (in place on P1; Q already includes b1) ----
__global__ void k_pq(float* __restrict__ P1, const float* __restrict__ Q) {
  int r = blockIdx.x;
  const float* q = Q + (size_t)(r >> 5) * HIDN;
  float* p = P1 + (size_t)r * HIDN;
  for (int n = threadIdx.x; n < HIDN; n += 256) p[n] += q[n];
}

__global__ void k_zero(float* __restrict__ p, int n) {
  int i = blockIdx.x * 256 + threadIdx.x;
  if (i < n) p[i] = 0.f;
}

// ---- layer-2 GEMM fused with layer-3 partial ----
// T3/T4 pipeline: TRIPLE-buffered staging via global_load_lds, counted
// s_waitcnt vmcnt(N) (never 0 in steady state) + raw s_barrier pairs, so
// stage loads for steps kt+1/kt+2 stay in flight across barriers instead of
// being drained every step by __syncthreads' implicit vmcnt(0).
// Per-wave issue per step: w0 = 4 loads (2 B + 1 P2 + 1 PQ1), w1..3 = 3.
// Steady wait = 2 steps in flight -> vmcnt(8) for w0, vmcnt(6) others.
// LDS: B[3][8192] @0 | P2s[3][4096] @24576 | PQ1s[3][1024] @36864 = 39936
__global__ __launch_bounds__(256, 3)
void k_gemm2(const float* __restrict__ PQ1, const float* __restrict__ P2,
             const unsigned short* __restrict__ W2T,
             const float* __restrict__ b2, const float* __restrict__ W3,
             float* __restrict__ Lraw) {
  __shared__ alignas(16) unsigned char LB[39936];
  int bx = blockIdx.x;
  int mt = bx / 12, nc = bx - mt * 12;
  int m0 = mt * 128, n0 = nc * 128;
  int tid = threadIdx.x, lane = tid & 63, w = tid >> 6;
  int bG = m0 >> 10;              // graph index (tiles never straddle graphs)
  int i0 = (m0 >> 5) & 31;        // first i-row of this mtile
  int ks = lane >> 4;             // k-slot 0..3 (8 f32 each)
  int r  = lane & 15;

  const int swcolB = ((lane & 3) ^ ((lane >> 3) & 3)) * 8;              // B source swizzle (bf16 elems)
  const int swcolP = (((lane >> 1) & 3) ^ ((lane >> 3) & 3)) * 8 + (lane & 1) * 4;  // P2s source swizzle (f32 elems)

  auto STAGE = [&](int kt, int buf) {
#pragma unroll
    for (int q = 0; q < 2; ++q) {
      int seg = w * 2 + q;
      int row = seg * 16 + (lane >> 2);
      gload_lds16(W2T + (size_t)(n0 + row) * HIDN + kt * 32 + swcolB,
                  LB + buf * 8192 + seg * 1024);
    }
    // P2 slice: 32 rows x 32 f32, quarter s = w (8 rows each), source col swizzled
    gload_lds16(P2 + (size_t)(bG * NPER + 8 * w + (lane >> 3)) * HIDN + kt * 32 + swcolP,
                LB + 24576 + buf * 4096 + w * 1024);
    // PQ1 slice: 8 rows x 32 f32, linear (broadcast-read later)
    if (w == 0)
      gload_lds16(PQ1 + (size_t)(bG * NPER + i0 + (lane >> 3)) * HIDN + kt * 32 + (lane & 7) * 4,
                  LB + 36864 + buf * 1024);
  };

  fv4 acc[4][4] = {};

  STAGE(0, 0);
  STAGE(1, 1);

  for (int kt = 0; kt < 92; ++kt) {
    int cur = kt % 3;
    if (kt + 2 < 92) STAGE(kt + 2, (kt + 2) % 3);

    // counted wait: drain only stage-kt's loads; keep kt+1/kt+2 in flight.
    if (kt < 90) {
      if (w == 0) asm volatile("s_waitcnt vmcnt(8)" ::: "memory");
      else        asm volatile("s_waitcnt vmcnt(6)" ::: "memory");
    } else {
      asm volatile("s_waitcnt vmcnt(0)" ::: "memory");  // tail drain (2 iters)
    }
    __builtin_amdgcn_s_barrier();
    asm volatile("" ::: "memory");  // pin LDS reads below the barrier

    const unsigned char* Bb = LB + cur * 8192;
    const unsigned char* Pb = LB + 24576 + cur * 4096;
    const unsigned char* Qb = LB + 36864 + cur * 1024;

    // operand reads from LDS
    int il0 = (w >> 1) * 2;
    int psw = (ks ^ (r & 3)) * 32;
    fv4 q0[2], q1[2], p0[2], p1[2];
#pragma unroll
    for (int h = 0; h < 2; ++h) {
      q0[h] = *(const fv4*)(Qb + il0 * 128 + ks * 32 + h * 16);        // broadcast
      q1[h] = *(const fv4*)(Qb + (il0 + 1) * 128 + ks * 32 + h * 16);  // broadcast
      p0[h] = *(const fv4*)(Pb + r * 128 + psw + h * 16);
      p1[h] = *(const fv4*)(Pb + (16 + r) * 128 + psw + h * 16);
    }
    bf16x8 bF[4];
#pragma unroll
    for (int nf = 0; nf < 4; ++nf) {
      int brow = (w & 1) * 64 + nf * 16 + r;
      int slot = ks ^ ((brow >> 1) & 3);
      bF[nf] = *(const bf16x8*)(Bb + brow * 64 + slot * 16);
    }

    // construct A fragments: relu(PQ1[i_loc] + P2[j]) -> bf16
    bf16x8 aF[4];
#pragma unroll
    for (int mf = 0; mf < 4; ++mf) {
      fv4 s0 = (mf & 2 ? q1[0] : q0[0]) + (mf & 1 ? p1[0] : p0[0]);
      fv4 s1 = (mf & 2 ? q1[1] : q0[1]) + (mf & 1 ? p1[1] : p0[1]);
      uiv4 u;
      u[0] = cvt_pk_bf16(fmaxf(s0[0], 0.f), fmaxf(s0[1], 0.f));
      u[1] = cvt_pk_bf16(fmaxf(s0[2], 0.f), fmaxf(s0[3], 0.f));
      u[2] = cvt_pk_bf16(fmaxf(s1[0], 0.f), fmaxf(s1[1], 0.f));
      u[3] = cvt_pk_bf16(fmaxf(s1[2], 0.f), fmaxf(s1[3], 0.f));
      aF[mf] = __builtin_bit_cast(bf16x8, u);
    }

    __builtin_amdgcn_s_setprio(1);
#pragma unroll
    for (int mf = 0; mf < 4; ++mf)
#pragma unroll
      for (int nf = 0; nf < 4; ++nf)
        acc[mf][nf] = __builtin_amdgcn_mfma_f32_16x16x32_bf16(aF[mf], bF[nf], acc[mf][nf], 0, 0, 0);
    __builtin_amdgcn_s_setprio(0);

    asm volatile("" ::: "memory");  // pin this step's LDS reads above barrier2
    __builtin_amdgcn_s_barrier();   // cur buffer free for restage next iter
  }

  // epilogue: h2 = relu(acc + b2); partial logits = h2 @ W3 chunk; wave reduce;
  // cross-wave LDS reduce; coalesced atomicAdd.
  float* red = (float*)LB;  // reuse (past final barrier)
  int nq = (w & 1) * 64;
#pragma unroll
  for (int mf = 0; mf < 4; ++mf) {
    float s[4][NA];
#pragma unroll
    for (int rr = 0; rr < 4; ++rr)
#pragma unroll
      for (int a = 0; a < NA; ++a) s[rr][a] = 0.f;
#pragma unroll
    for (int nf = 0; nf < 4; ++nf) {
      int n = n0 + nq + nf * 16 + r;
      if (n < FEAT) {  // boundary multiple of 16 -> uniform per nf
        float bv = b2[n];
        float w3r[NA];
#pragma unroll
        for (int a = 0; a < NA; ++a) w3r[a] = W3[n * NA + a];
#pragma unroll
        for (int rr = 0; rr < 4; ++rr) {
          float h = fmaxf(acc[mf][nf][rr] + bv, 0.f);
#pragma unroll
          for (int a = 0; a < NA; ++a) s[rr][a] += h * w3r[a];
        }
      }
    }
#pragma unroll
    for (int off = 1; off < 16; off <<= 1)
#pragma unroll
      for (int rr = 0; rr < 4; ++rr)
#pragma unroll
        for (int a = 0; a < NA; ++a) s[rr][a] += __shfl_xor(s[rr][a], off, 64);
    int a = r;
    if (a < NA) {
#pragma unroll
      for (int rr = 0; rr < 4; ++rr)
        red[w * 704 + (mf * 16 + ks * 4 + rr) * NA + a] = s[rr][a];
    }
  }
  __syncthreads();
  for (int e = tid; e < 128 * NA; e += 256) {
    int row = e / NA, a = e - row * NA;
    int wr = row >> 6, rr = row & 63;
    float v = red[(wr * 2 + 0) * 704 + rr * NA + a] + red[(wr * 2 + 1) * 704 + rr * NA + a];
    atomicAdd(&Lraw[(size_t)(m0 + row) * NA + a], v);
  }
}

// ---- symmetrize + b3 ----
__global__ void k_sym(const float* __restrict__ Lraw, const float* __restrict__ b3,
                      float* __restrict__ out) {
  int e = blockIdx.x * 256 + threadIdx.x;
  if (e >= MEDGE * NA) return;
  int m = e / NA, a = e - m * NA;
  int msw = (m & ~1023) | ((m & 31) << 5) | ((m >> 5) & 31);
  out[e] = 0.5f * (Lraw[e] + Lraw[(size_t)msw * NA + a]) + b3[a];
}

extern "C" void kernel_launch(void* const* d_in, const int* in_sizes, int n_in,
                              void* d_out, int out_size, void* d_ws, size_t ws_size,
                              hipStream_t stream) {
  const int*   idx      = (const int*)d_in[0];
  const int*   mlt      = (const int*)d_in[1];
  const float* z        = (const float*)d_in[2];
  const float* id_emb   = (const float*)d_in[3];
  const float* mult_emb = (const float*)d_in[4];
  const float* W1       = (const float*)d_in[5];
  const float* b1       = (const float*)d_in[6];
  const float* W2       = (const float*)d_in[7];
  const float* b2       = (const float*)d_in[8];
  const float* W3       = (const float*)d_in[9];
  const float* b3       = (const float*)d_in[10];
  float* out = (float*)d_out;

  uint8_t* ws = (uint8_t*)d_ws;
  size_t o = 0;
  auto alloc = [&](size_t bytes) { size_t r = o; o += (bytes + 255) & ~(size_t)255; return r; };
  size_t oW1T = alloc((size_t)HIDN * FEAT * 2);       // bf16 [2944][1472]
  size_t oW2T = alloc((size_t)FEATP * HIDN * 2);      // bf16 [1536][2944]
  size_t oXB  = alloc((size_t)NROWS * DNODE * 2);     // bf16 [2048][320]
  size_t oZA  = alloc((size_t)128 * 832 * 2);         // bf16 [128][832]
  size_t oAG  = alloc((size_t)NBG * DNODE * 4);       // f32  [64][320]
  size_t oP1  = alloc((size_t)NROWS * HIDN * 4);      // f32  [2048][2944]
  size_t oP2  = alloc((size_t)NROWS * HIDN * 4);
  size_t oQ   = alloc((size_t)NBG * HIDN * 4);
  size_t oLR  = alloc((size_t)MEDGE * NA * 4);
  if (ws_size < o) return;  // insufficient workspace

  unsigned short* W1T = (unsigned short*)(ws + oW1T);
  unsigned short* W2T = (unsigned short*)(ws + oW2T);
  unsigned short* xb  = (unsigned short*)(ws + oXB);
  unsigned short* za  = (unsigned short*)(ws + oZA);
  float* agg = (float*)(ws + oAG);
  float* P1  = (float*)(ws + oP1);
  float* P2  = (float*)(ws + oP2);
  float* Qm  = (float*)(ws + oQ);
  float* LR  = (float*)(ws + oLR);

  k_transpose_bf16<<<dim3(FEAT / 64, HIDN / 64), 256, 0, stream>>>(W1, W1T, FEAT, HIDN, HIDN);
  k_transpose_bf16<<<dim3(HIDN / 64, FEATP / 64), 256, 0, stream>>>(W2, W2T, HIDN, FEAT, FEATP);
  k_embed<<<NROWS, 256, 0, stream>>>(idx, mlt, id_emb, mult_emb, xb);
  k_agg<<<NBG, 256, 0, stream>>>(xb, agg);
  k_za<<<128, 256, 0, stream>>>(z, agg, za);
  k_gemm1<<<16 * 23, 256, 0, stream>>>(xb, DNODE, NROWS, W1T, 0, 10, P1, nullptr);
  k_gemm1<<<16 * 23, 256, 0, stream>>>(xb, DNODE, NROWS, W1T, 320, 10, P2, nullptr);
  k_gemm1<<<1 * 23, 256, 0, stream>>>(za, 832, NBG, W1T, 640, 26, Qm, b1);
  k_pq<<<NROWS, 256, 0, stream>>>(P1, Qm);
  k_zero<<<(MEDGE * NA + 255) / 256, 256, 0, stream>>>(LR, MEDGE * NA);
  k_gemm2<<<512 * 12, 256, 0, stream>>>(P1, P2, W2T, b2, W3, LR);
  k_sym<<<(MEDGE * NA + 255) / 256, 256, 0, stream>>>(LR, b3, out);
}

// Round 2
// 1317.098 us; speedup vs baseline: 1.0045x; 1.0045x over previous
//
#include <hip/hip_runtime.h>
#include <stdint.h>

// ---- problem constants ----
#define NBG   64      // graphs
#define NPER  32      // nodes per graph
#define DNODE 320
#define FEAT  1472
#define HIDN  2944
#define FEATP 1536    // FEAT padded to x128 for layer-2 N
#define NA    11
#define NROWS 2048    // NBG*NPER
#define MEDGE 65536   // NBG*NPER*NPER

typedef __attribute__((ext_vector_type(8))) short    bf16x8;
typedef __attribute__((ext_vector_type(4))) float    fv4;
typedef __attribute__((ext_vector_type(4))) unsigned uiv4;

__device__ __forceinline__ unsigned short f2bf(float f) {
  unsigned u = __builtin_bit_cast(unsigned, f);
  u += 0x7fffu + ((u >> 16) & 1u);
  return (unsigned short)(u >> 16);
}
__device__ __forceinline__ float bf2f(unsigned short h) {
  unsigned u = ((unsigned)h) << 16;
  return __builtin_bit_cast(float, u);
}
__device__ __forceinline__ unsigned cvt_pk_bf16(float lo, float hi) {
  unsigned r;
  asm("v_cvt_pk_bf16_f32 %0, %1, %2" : "=v"(r) : "v"(lo), "v"(hi));
  return r;
}
// async global->LDS, 16B per lane; lds base wave-uniform (HW adds lane*16)
__device__ __forceinline__ void gload_lds16(const void* g, void* l) {
  __builtin_amdgcn_global_load_lds((const __attribute__((address_space(1))) void*)g,
                                   (__attribute__((address_space(3))) void*)l, 16, 0, 0);
}

// ---- transpose f32 [K][N] -> bf16 [Npad][K]; rows n>=N zero-filled ----
__global__ void k_transpose_bf16(const float* __restrict__ src, unsigned short* __restrict__ dst,
                                 int K, int N, int Npad) {
  __shared__ float tile[64][65];
  int k0 = blockIdx.x * 64, n0 = blockIdx.y * 64;
  int r = threadIdx.x >> 2, cb = (threadIdx.x & 3) * 16;
  const float* srow = src + (size_t)(k0 + r) * N + n0 + cb;
#pragma unroll
  for (int c = 0; c < 16; ++c) {
    int n = n0 + cb + c;
    tile[r][cb + c] = (n < N) ? srow[c] : 0.f;
  }
  __syncthreads();
  unsigned short* drow = dst + (size_t)(n0 + r) * K + k0 + cb;
#pragma unroll
  for (int c = 0; c < 16; ++c) drow[c] = f2bf(tile[cb + c][r]);
}

// ---- embeddings -> xb bf16 [2048][320] ----
__global__ void k_embed(const int* __restrict__ idx, const int* __restrict__ mlt,
                        const float* __restrict__ id_emb, const float* __restrict__ mult_emb,
                        unsigned short* __restrict__ xb) {
  int t = blockIdx.x, c = threadIdx.x;
  int iv = idx[t], mv = mlt[t];
  xb[t * DNODE + c] = f2bf(id_emb[iv * 256 + c]);
  if (c < 64) xb[t * DNODE + 256 + c] = f2bf(mult_emb[mv * 64 + c]);
}

// ---- agg f32 [64][320] = mean over 32 nodes ----
__global__ void k_agg(const unsigned short* __restrict__ xb, float* __restrict__ agg) {
  int b = blockIdx.x;
  for (int d = threadIdx.x; d < DNODE; d += 256) {
    float s = 0.f;
    for (int i = 0; i < NPER; ++i) s += bf2f(xb[(b * NPER + i) * DNODE + d]);
    agg[b * DNODE + d] = s * (1.f / 32.f);
  }
}

// ---- za bf16 [128][832] = [z | agg], rows 64..127 zero ----
__global__ void k_za(const float* __restrict__ z, const float* __restrict__ agg,
                     unsigned short* __restrict__ za) {
  int b = blockIdx.x;
  for (int c = threadIdx.x; c < 832; c += 256) {
    unsigned short v = 0;
    if (b < NBG) v = (c < 512) ? f2bf(z[b * 512 + c]) : f2bf(agg[b * DNODE + (c - 512)]);
    za[b * 832 + c] = v;
  }
}

// ---- layer-1 GEMM: C[M][2944] (f32) = A(bf16,[M][sA] slice) @ W1T(bf16 [2944][1472])^T ----
__global__ void k_gemm1(const unsigned short* __restrict__ A, int sA, int Mrows,
                        const unsigned short* __restrict__ W1T, int kOff, int Ksteps,
                        float* __restrict__ C, const float* __restrict__ bias) {
  __shared__ alignas(16) unsigned short Als[128 * 32];
  __shared__ alignas(16) unsigned short Bls[128 * 32];
  int bx = blockIdx.x;
  int mt = bx / 23, nc = bx - mt * 23;
  int m0 = mt * 128, n0 = nc * 128;
  int tid = threadIdx.x, lane = tid & 63, w = tid >> 6;

  fv4 acc[4][4] = {};
  for (int kt = 0; kt < Ksteps; ++kt) {
    int k0 = kt * 32;
    __syncthreads();
#pragma unroll
    for (int q = 0; q < 2; ++q) {
      int seg = w * 2 + q;
      int row = seg * 16 + (lane >> 2);
      int col = (lane & 3) * 8;
      gload_lds16(A + (size_t)(m0 + row) * sA + k0 + col, &Als[seg * 512]);
      gload_lds16(W1T + (size_t)(n0 + row) * FEAT + kOff + k0 + col, &Bls[seg * 512]);
    }
    __syncthreads();
    bf16x8 aF[4], bF[4];
#pragma unroll
    for (int mf = 0; mf < 4; ++mf)
      aF[mf] = *(const bf16x8*)&Als[((w >> 1) * 64 + mf * 16 + (lane & 15)) * 32 + (lane >> 4) * 8];
#pragma unroll
    for (int nf = 0; nf < 4; ++nf)
      bF[nf] = *(const bf16x8*)&Bls[((w & 1) * 64 + nf * 16 + (lane & 15)) * 32 + (lane >> 4) * 8];
#pragma unroll
    for (int mf = 0; mf < 4; ++mf)
#pragma unroll
      for (int nf = 0; nf < 4; ++nf)
        acc[mf][nf] = __builtin_amdgcn_mfma_f32_16x16x32_bf16(aF[mf], bF[nf], acc[mf][nf], 0, 0, 0);
  }
  int mq = (w >> 1) * 64, nq = (w & 1) * 64;
#pragma unroll
  for (int mf = 0; mf < 4; ++mf)
#pragma unroll
    for (int nf = 0; nf < 4; ++nf) {
      int n = n0 + nq + nf * 16 + (lane & 15);
      float bv = bias ? bias[n] : 0.f;
#pragma unroll
      for (int r = 0; r < 4; ++r) {
        int m = m0 + mq + mf * 16 + (lane >> 4) * 4 + r;
        if (m < Mrows) C[(size_t)m * HIDN + n] = acc[mf][nf][r] + bv;
      }
    }
}

// ---- PQ1 = P1 + Q[b] (in place on P1; Q already includes b1) ----
__global__ void k_pq(float* __restrict__ P1, const float* __restrict__ Q) {
  int r = blockIdx.x;
  const float* q = Q + (size_t)(r >> 5) * HIDN;
  float* p = P1 + (size_t)r * HIDN;
  for (int n = threadIdx.x; n < HIDN; n += 256) p[n] += q[n];
}

__global__ void k_zero(float* __restrict__ p, int n) {
  int i = blockIdx.x * 256 + threadIdx.x;
  if (i < n) p[i] = 0.f;
}

// ---- materialize A bf16 [65536][2944]: A[bi*32+j][k] = relu(PQ1[bi][k] + P2[b*32+j][k]) ----
// one block per (b,i) row-pair; PQ1 row stays L1-resident across the j loop.
__global__ void k_build_A(const float* __restrict__ PQ1, const float* __restrict__ P2,
                          unsigned short* __restrict__ Abf) {
  int bi = blockIdx.x;              // 0..2047 = b*32 + i
  int b = bi >> 5;
  const float* qrow = PQ1 + (size_t)bi * HIDN;
  const float* pbase = P2 + (size_t)(b * NPER) * HIDN;
  unsigned short* abase = Abf + (size_t)bi * NPER * HIDN;
  for (int j = 0; j < NPER; ++j) {
    const float* prow = pbase + (size_t)j * HIDN;
    unsigned short* arow = abase + (size_t)j * HIDN;
    for (int kc = threadIdx.x; kc < HIDN / 8; kc += 256) {
      fv4 q0 = *(const fv4*)(qrow + kc * 8);
      fv4 q1 = *(const fv4*)(qrow + kc * 8 + 4);
      fv4 p0 = *(const fv4*)(prow + kc * 8);
      fv4 p1 = *(const fv4*)(prow + kc * 8 + 4);
      fv4 s0 = q0 + p0, s1 = q1 + p1;
      uiv4 u;
      u[0] = cvt_pk_bf16(fmaxf(s0[0], 0.f), fmaxf(s0[1], 0.f));
      u[1] = cvt_pk_bf16(fmaxf(s0[2], 0.f), fmaxf(s0[3], 0.f));
      u[2] = cvt_pk_bf16(fmaxf(s1[0], 0.f), fmaxf(s1[1], 0.f));
      u[3] = cvt_pk_bf16(fmaxf(s1[2], 0.f), fmaxf(s1[3], 0.f));
      *(uiv4*)(arow + kc * 8) = u;
    }
  }
}

// ---- layer-2 GEMM (materialized A) fused with layer-3 partial ----
// k_gemm1-proven 2-barrier structure; XCD-chunked block swizzle so the 12
// nc-blocks sharing an A-tile are dispatch-adjacent (L2/L3 reuse of A).
// Epilogue: fused W3 reduce, PLAIN store to per-nc partial slice (no atomics).
__global__ __launch_bounds__(256, 3)
void k_gemm2m(const unsigned short* __restrict__ A, const unsigned short* __restrict__ W2T,
              const float* __restrict__ b2, const float* __restrict__ W3,
              float* __restrict__ LRp) {
  __shared__ alignas(16) unsigned char LB[16384];
  unsigned short* Als = (unsigned short*)LB;            // [128*32]
  unsigned short* Bls = (unsigned short*)(LB + 8192);   // [128*32]
  int raw = blockIdx.x;
  int bx = (raw & 7) * 768 + (raw >> 3);   // bijective: 6144 % 8 == 0
  int mt = bx / 12, nc = bx - mt * 12;
  int m0 = mt * 128, n0 = nc * 128;
  int tid = threadIdx.x, lane = tid & 63, w = tid >> 6;
  int r = lane & 15, ks = lane >> 4;

  fv4 acc[4][4] = {};
  for (int kt = 0; kt < 92; ++kt) {
    int k0 = kt * 32;
    __syncthreads();
#pragma unroll
    for (int q = 0; q < 2; ++q) {
      int seg = w * 2 + q;
      int row = seg * 16 + (lane >> 2);
      int col = (lane & 3) * 8;
      gload_lds16(A + (size_t)(m0 + row) * HIDN + k0 + col, &Als[seg * 512]);
      gload_lds16(W2T + (size_t)(n0 + row) * HIDN + k0 + col, &Bls[seg * 512]);
    }
    __syncthreads();
    bf16x8 aF[4], bF[4];
#pragma unroll
    for (int mf = 0; mf < 4; ++mf)
      aF[mf] = *(const bf16x8*)&Als[((w >> 1) * 64 + mf * 16 + r) * 32 + ks * 8];
#pragma unroll
    for (int nf = 0; nf < 4; ++nf)
      bF[nf] = *(const bf16x8*)&Bls[((w & 1) * 64 + nf * 16 + r) * 32 + ks * 8];
#pragma unroll
    for (int mf = 0; mf < 4; ++mf)
#pragma unroll
      for (int nf = 0; nf < 4; ++nf)
        acc[mf][nf] = __builtin_amdgcn_mfma_f32_16x16x32_bf16(aF[mf], bF[nf], acc[mf][nf], 0, 0, 0);
  }
  __syncthreads();  // all waves done reading Als/Bls before red reuse

  float* red = (float*)LB;
  int nq = (w & 1) * 64;
#pragma unroll
  for (int mf = 0; mf < 4; ++mf) {
    float s[4][NA];
#pragma unroll
    for (int rr = 0; rr < 4; ++rr)
#pragma unroll
      for (int a = 0; a < NA; ++a) s[rr][a] = 0.f;
#pragma unroll
    for (int nf = 0; nf < 4; ++nf) {
      int n = n0 + nq + nf * 16 + r;
      if (n < FEAT) {  // boundary multiple of 16 -> uniform per nf
        float bv = b2[n];
        float w3r[NA];
#pragma unroll
        for (int a = 0; a < NA; ++a) w3r[a] = W3[n * NA + a];
#pragma unroll
        for (int rr = 0; rr < 4; ++rr) {
          float h = fmaxf(acc[mf][nf][rr] + bv, 0.f);
#pragma unroll
          for (int a = 0; a < NA; ++a) s[rr][a] += h * w3r[a];
        }
      }
    }
#pragma unroll
    for (int off = 1; off < 16; off <<= 1)
#pragma unroll
      for (int rr = 0; rr < 4; ++rr)
#pragma unroll
        for (int a = 0; a < NA; ++a) s[rr][a] += __shfl_xor(s[rr][a], off, 64);
    int a = r;
    if (a < NA) {
#pragma unroll
      for (int rr = 0; rr < 4; ++rr)
        red[w * 704 + (mf * 16 + ks * 4 + rr) * NA + a] = s[rr][a];
    }
  }
  __syncthreads();
  for (int e = tid; e < 128 * NA; e += 256) {
    int row = e / NA, a = e - row * NA;
    int wr = row >> 6, rr = row & 63;
    float v = red[(wr * 2 + 0) * 704 + rr * NA + a] + red[(wr * 2 + 1) * 704 + rr * NA + a];
    LRp[(size_t)nc * (MEDGE * NA) + (size_t)(m0 + row) * NA + a] = v;
  }
}

// ---- layer-2 GEMM with on-the-fly A (fallback, round-0 structure) ----
// PARTIAL=true: plain store to per-nc slice; false: atomicAdd into single slice.
template <bool PARTIAL>
__global__ __launch_bounds__(256, 3)
void k_gemm2(const float* __restrict__ PQ1, const float* __restrict__ P2,
             const unsigned short* __restrict__ W2T,
             const float* __restrict__ b2, const float* __restrict__ W3,
             float* __restrict__ Lout) {
  __shared__ alignas(16) unsigned char LB[26624];
  int bx = blockIdx.x;
  int mt = bx / 12, nc = bx - mt * 12;
  int m0 = mt * 128, n0 = nc * 128;
  int tid = threadIdx.x, lane = tid & 63, w = tid >> 6;
  int bG = m0 >> 10;
  int i0 = (m0 >> 5) & 31;
  int ks = lane >> 4;
  int r  = lane & 15;

  const int swcolB = ((lane & 3) ^ ((lane >> 3) & 3)) * 8;
  const int swcolP = (((lane >> 1) & 3) ^ ((lane >> 3) & 3)) * 8 + (lane & 1) * 4;

  auto STAGEB = [&](int kt, int buf) {
#pragma unroll
    for (int q = 0; q < 2; ++q) {
      int seg = w * 2 + q;
      int row = seg * 16 + (lane >> 2);
      gload_lds16(W2T + (size_t)(n0 + row) * HIDN + kt * 32 + swcolB,
                  LB + buf * 8192 + seg * 1024);
    }
  };
  auto STAGESRC = [&](int kt, int buf) {
    gload_lds16(P2 + (size_t)(bG * NPER + 8 * w + (lane >> 3)) * HIDN + kt * 32 + swcolP,
                LB + 16384 + buf * 4096 + w * 1024);
    if (w == 0)
      gload_lds16(PQ1 + (size_t)(bG * NPER + i0 + (lane >> 3)) * HIDN + kt * 32 + (lane & 7) * 4,
                  LB + 24576 + buf * 1024);
  };

  fv4 acc[4][4] = {};

  STAGEB(0, 0);
  STAGESRC(0, 0);
  __syncthreads();

  for (int kt = 0; kt < 92; ++kt) {
    int cur = kt & 1, nxt = cur ^ 1;
    if (kt < 91) { STAGEB(kt + 1, nxt); STAGESRC(kt + 1, nxt); }

    const unsigned char* Bb = LB + cur * 8192;
    const unsigned char* Pb = LB + 16384 + cur * 4096;
    const unsigned char* Qb = LB + 24576 + cur * 1024;

    int il0 = (w >> 1) * 2;
    int psw = (ks ^ (r & 3)) * 32;
    fv4 q0[2], q1[2], p0[2], p1[2];
#pragma unroll
    for (int h = 0; h < 2; ++h) {
      q0[h] = *(const fv4*)(Qb + il0 * 128 + ks * 32 + h * 16);
      q1[h] = *(const fv4*)(Qb + (il0 + 1) * 128 + ks * 32 + h * 16);
      p0[h] = *(const fv4*)(Pb + r * 128 + psw + h * 16);
      p1[h] = *(const fv4*)(Pb + (16 + r) * 128 + psw + h * 16);
    }
    bf16x8 bF[4];
#pragma unroll
    for (int nf = 0; nf < 4; ++nf) {
      int brow = (w & 1) * 64 + nf * 16 + r;
      int slot = ks ^ ((brow >> 1) & 3);
      bF[nf] = *(const bf16x8*)(Bb + brow * 64 + slot * 16);
    }

    bf16x8 aF[4];
#pragma unroll
    for (int mf = 0; mf < 4; ++mf) {
      fv4 s0 = (mf & 2 ? q1[0] : q0[0]) + (mf & 1 ? p1[0] : p0[0]);
      fv4 s1 = (mf & 2 ? q1[1] : q0[1]) + (mf & 1 ? p1[1] : p0[1]);
      uiv4 u;
      u[0] = cvt_pk_bf16(fmaxf(s0[0], 0.f), fmaxf(s0[1], 0.f));
      u[1] = cvt_pk_bf16(fmaxf(s0[2], 0.f), fmaxf(s0[3], 0.f));
      u[2] = cvt_pk_bf16(fmaxf(s1[0], 0.f), fmaxf(s1[1], 0.f));
      u[3] = cvt_pk_bf16(fmaxf(s1[2], 0.f), fmaxf(s1[3], 0.f));
      aF[mf] = __builtin_bit_cast(bf16x8, u);
    }

#pragma unroll
    for (int mf = 0; mf < 4; ++mf)
#pragma unroll
      for (int nf = 0; nf < 4; ++nf)
        acc[mf][nf] = __builtin_amdgcn_mfma_f32_16x16x32_bf16(aF[mf], bF[nf], acc[mf][nf], 0, 0, 0);
    __syncthreads();
  }
  __syncthreads();  // guard LB reuse against laggard waves

  float* red = (float*)LB;
  int nq = (w & 1) * 64;
#pragma unroll
  for (int mf = 0; mf < 4; ++mf) {
    float s[4][NA];
#pragma unroll
    for (int rr = 0; rr < 4; ++rr)
#pragma unroll
      for (int a = 0; a < NA; ++a) s[rr][a] = 0.f;
#pragma unroll
    for (int nf = 0; nf < 4; ++nf) {
      int n = n0 + nq + nf * 16 + r;
      if (n < FEAT) {
        float bv = b2[n];
        float w3r[NA];
#pragma unroll
        for (int a = 0; a < NA; ++a) w3r[a] = W3[n * NA + a];
#pragma unroll
        for (int rr = 0; rr < 4; ++rr) {
          float h = fmaxf(acc[mf][nf][rr] + bv, 0.f);
#pragma unroll
          for (int a = 0; a < NA; ++a) s[rr][a] += h * w3r[a];
        }
      }
    }
#pragma unroll
    for (int off = 1; off < 16; off <<= 1)
#pragma unroll
      for (int rr = 0; rr < 4; ++rr)
#pragma unroll
        for (int a = 0; a < NA; ++a) s[rr][a] += __shfl_xor(s[rr][a], off, 64);
    int a = r;
    if (a < NA) {
#pragma unroll
      for (int rr = 0; rr < 4; ++rr)
        red[w * 704 + (mf * 16 + ks * 4 + rr) * NA + a] = s[rr][a];
    }
  }
  __syncthreads();
  for (int e = tid; e < 128 * NA; e += 256) {
    int row = e / NA, a = e - row * NA;
    int wr = row >> 6, rr = row & 63;
    float v = red[(wr * 2 + 0) * 704 + rr * NA + a] + red[(wr * 2 + 1) * 704 + rr * NA + a];
    if (PARTIAL)
      Lout[(size_t)nc * (MEDGE * NA) + (size_t)(m0 + row) * NA + a] = v;
    else
      atomicAdd(&Lout[(size_t)(m0 + row) * NA + a], v);
  }
}

// ---- symmetrize + b3, summing NS partial slices ----
template <int NS>
__global__ void k_sym(const float* __restrict__ LRp, const float* __restrict__ b3,
                      float* __restrict__ out) {
  int e = blockIdx.x * 256 + threadIdx.x;
  if (e >= MEDGE * NA) return;
  int m = e / NA, a = e - m * NA;
  int msw = (m & ~1023) | ((m & 31) << 5) | ((m >> 5) & 31);
  float s = 0.f;
#pragma unroll
  for (int t = 0; t < NS; ++t)
    s += LRp[(size_t)t * (MEDGE * NA) + e] + LRp[(size_t)t * (MEDGE * NA) + (size_t)msw * NA + a];
  out[e] = 0.5f * s + b3[a];
}

extern "C" void kernel_launch(void* const* d_in, const int* in_sizes, int n_in,
                              void* d_out, int out_size, void* d_ws, size_t ws_size,
                              hipStream_t stream) {
  const int*   idx      = (const int*)d_in[0];
  const int*   mlt      = (const int*)d_in[1];
  const float* z        = (const float*)d_in[2];
  const float* id_emb   = (const float*)d_in[3];
  const float* mult_emb = (const float*)d_in[4];
  const float* W1       = (const float*)d_in[5];
  const float* b1       = (const float*)d_in[6];
  const float* W2       = (const float*)d_in[7];
  const float* b2       = (const float*)d_in[8];
  const float* W3       = (const float*)d_in[9];
  const float* b3       = (const float*)d_in[10];
  float* out = (float*)d_out;

  uint8_t* ws = (uint8_t*)d_ws;
  size_t o = 0;
  auto alloc = [&](size_t bytes) { size_t r = o; o += (bytes + 255) & ~(size_t)255; return r; };
  size_t oW1T = alloc((size_t)HIDN * FEAT * 2);       // bf16 [2944][1472]
  size_t oW2T = alloc((size_t)FEATP * HIDN * 2);      // bf16 [1536][2944]
  size_t oXB  = alloc((size_t)NROWS * DNODE * 2);     // bf16 [2048][320]
  size_t oZA  = alloc((size_t)128 * 832 * 2);         // bf16 [128][832]
  size_t oAG  = alloc((size_t)NBG * DNODE * 4);       // f32  [64][320]
  size_t oP1  = alloc((size_t)NROWS * HIDN * 4);      // f32  [2048][2944]
  size_t oP2  = alloc((size_t)NROWS * HIDN * 4);
  size_t oQ   = alloc((size_t)NBG * HIDN * 4);
  size_t oLRp = alloc((size_t)12 * MEDGE * NA * 4);   // 12 partial slices (A/B); C uses slice 0
  size_t needB = o;
  size_t oA   = alloc((size_t)MEDGE * HIDN * 2);      // bf16 A [65536][2944]
  size_t needA = o;
  size_t needC = oLRp + (((size_t)MEDGE * NA * 4 + 255) & ~(size_t)255);
  if (ws_size < needC) return;  // insufficient workspace
  int tier = (ws_size >= needA) ? 0 : (ws_size >= needB ? 1 : 2);

  unsigned short* W1T = (unsigned short*)(ws + oW1T);
  unsigned short* W2T = (unsigned short*)(ws + oW2T);
  unsigned short* xb  = (unsigned short*)(ws + oXB);
  unsigned short* za  = (unsigned short*)(ws + oZA);
  float* agg = (float*)(ws + oAG);
  float* P1  = (float*)(ws + oP1);
  float* P2  = (float*)(ws + oP2);
  float* Qm  = (float*)(ws + oQ);
  float* LRp = (float*)(ws + oLRp);
  unsigned short* Abf = (unsigned short*)(ws + oA);

  k_transpose_bf16<<<dim3(FEAT / 64, HIDN / 64), 256, 0, stream>>>(W1, W1T, FEAT, HIDN, HIDN);
  k_transpose_bf16<<<dim3(HIDN / 64, FEATP / 64), 256, 0, stream>>>(W2, W2T, HIDN, FEAT, FEATP);
  k_embed<<<NROWS, 256, 0, stream>>>(idx, mlt, id_emb, mult_emb, xb);
  k_agg<<<NBG, 256, 0, stream>>>(xb, agg);
  k_za<<<128, 256, 0, stream>>>(z, agg, za);
  k_gemm1<<<16 * 23, 256, 0, stream>>>(xb, DNODE, NROWS, W1T, 0, 10, P1, nullptr);
  k_gemm1<<<16 * 23, 256, 0, stream>>>(xb, DNODE, NROWS, W1T, 320, 10, P2, nullptr);
  k_gemm1<<<1 * 23, 256, 0, stream>>>(za, 832, NBG, W1T, 640, 26, Qm, b1);
  k_pq<<<NROWS, 256, 0, stream>>>(P1, Qm);

  if (tier == 0) {
    k_build_A<<<NROWS, 256, 0, stream>>>(P1, P2, Abf);
    k_gemm2m<<<512 * 12, 256, 0, stream>>>(Abf, W2T, b2, W3, LRp);
    k_sym<12><<<(MEDGE * NA + 255) / 256, 256, 0, stream>>>(LRp, b3, out);
  } else if (tier == 1) {
    k_gemm2<true><<<512 * 12, 256, 0, stream>>>(P1, P2, W2T, b2, W3, LRp);
    k_sym<12><<<(MEDGE * NA + 255) / 256, 256, 0, stream>>>(LRp, b3, out);
  } else {
    k_zero<<<(MEDGE * NA + 255) / 256, 256, 0, stream>>>(LRp, MEDGE * NA);
    k_gemm2<false><<<512 * 12, 256, 0, stream>>>(P1, P2, W2T, b2, W3, LRp);
    k_sym<1><<<(MEDGE * NA + 255) / 256, 256, 0, stream>>>(LRp, b3, out);
  }
}

// Round 3
// 1154.099 us; speedup vs baseline: 1.1464x; 1.1412x over previous
//
#include <hip/hip_runtime.h>
#include <stdint.h>

// ---- problem constants ----
#define NBG   64      // graphs
#define NPER  32      // nodes per graph
#define DNODE 320
#define FEAT  1472
#define HIDN  2944
#define FEATP 1536    // FEAT padded to x128 for layer-2 N
#define NA    11
#define NROWS 2048    // NBG*NPER
#define MEDGE 65536   // NBG*NPER*NPER

typedef __attribute__((ext_vector_type(8))) short    bf16x8;
typedef __attribute__((ext_vector_type(4))) float    fv4;
typedef __attribute__((ext_vector_type(4))) unsigned uiv4;

__device__ __forceinline__ unsigned short f2bf(float f) {
  unsigned u = __builtin_bit_cast(unsigned, f);
  u += 0x7fffu + ((u >> 16) & 1u);
  return (unsigned short)(u >> 16);
}
__device__ __forceinline__ float bf2f(unsigned short h) {
  unsigned u = ((unsigned)h) << 16;
  return __builtin_bit_cast(float, u);
}
__device__ __forceinline__ unsigned cvt_pk_bf16(float lo, float hi) {
  unsigned r;
  asm("v_cvt_pk_bf16_f32 %0, %1, %2" : "=v"(r) : "v"(lo), "v"(hi));
  return r;
}
// async global->LDS, 16B per lane; lds base wave-uniform (HW adds lane*16)
__device__ __forceinline__ void gload_lds16(const void* g, void* l) {
  __builtin_amdgcn_global_load_lds((const __attribute__((address_space(1))) void*)g,
                                   (__attribute__((address_space(3))) void*)l, 16, 0, 0);
}

// ---- transpose f32 [K][N] -> bf16 [Npad][K]; rows n>=N zero-filled ----
__global__ void k_transpose_bf16(const float* __restrict__ src, unsigned short* __restrict__ dst,
                                 int K, int N, int Npad) {
  __shared__ float tile[64][65];
  int k0 = blockIdx.x * 64, n0 = blockIdx.y * 64;
  int r = threadIdx.x >> 2, cb = (threadIdx.x & 3) * 16;
  const float* srow = src + (size_t)(k0 + r) * N + n0 + cb;
#pragma unroll
  for (int c = 0; c < 16; ++c) {
    int n = n0 + cb + c;
    tile[r][cb + c] = (n < N) ? srow[c] : 0.f;
  }
  __syncthreads();
  unsigned short* drow = dst + (size_t)(n0 + r) * K + k0 + cb;
#pragma unroll
  for (int c = 0; c < 16; ++c) drow[c] = f2bf(tile[cb + c][r]);
}

// ---- embeddings -> xb bf16 [2048][320] ----
__global__ void k_embed(const int* __restrict__ idx, const int* __restrict__ mlt,
                        const float* __restrict__ id_emb, const float* __restrict__ mult_emb,
                        unsigned short* __restrict__ xb) {
  int t = blockIdx.x, c = threadIdx.x;
  int iv = idx[t], mv = mlt[t];
  xb[t * DNODE + c] = f2bf(id_emb[iv * 256 + c]);
  if (c < 64) xb[t * DNODE + 256 + c] = f2bf(mult_emb[mv * 64 + c]);
}

// ---- agg f32 [64][320] = mean over 32 nodes ----
__global__ void k_agg(const unsigned short* __restrict__ xb, float* __restrict__ agg) {
  int b = blockIdx.x;
  for (int d = threadIdx.x; d < DNODE; d += 256) {
    float s = 0.f;
    for (int i = 0; i < NPER; ++i) s += bf2f(xb[(b * NPER + i) * DNODE + d]);
    agg[b * DNODE + d] = s * (1.f / 32.f);
  }
}

// ---- za bf16 [128][832] = [z | agg], rows 64..127 zero ----
__global__ void k_za(const float* __restrict__ z, const float* __restrict__ agg,
                     unsigned short* __restrict__ za) {
  int b = blockIdx.x;
  for (int c = threadIdx.x; c < 832; c += 256) {
    unsigned short v = 0;
    if (b < NBG) v = (c < 512) ? f2bf(z[b * 512 + c]) : f2bf(agg[b * DNODE + (c - 512)]);
    za[b * 832 + c] = v;
  }
}

// ---- layer-1 GEMM: C[M][2944] (f32) = A(bf16,[M][sA] slice) @ W1T(bf16 [2944][1472])^T ----
__global__ void k_gemm1(const unsigned short* __restrict__ A, int sA, int Mrows,
                        const unsigned short* __restrict__ W1T, int kOff, int Ksteps,
                        float* __restrict__ C, const float* __restrict__ bias) {
  __shared__ alignas(16) unsigned short Als[128 * 32];
  __shared__ alignas(16) unsigned short Bls[128 * 32];
  int bx = blockIdx.x;
  int mt = bx / 23, nc = bx - mt * 23;
  int m0 = mt * 128, n0 = nc * 128;
  int tid = threadIdx.x, lane = tid & 63, w = tid >> 6;

  fv4 acc[4][4] = {};
  for (int kt = 0; kt < Ksteps; ++kt) {
    int k0 = kt * 32;
    __syncthreads();
#pragma unroll
    for (int q = 0; q < 2; ++q) {
      int seg = w * 2 + q;
      int row = seg * 16 + (lane >> 2);
      int col = (lane & 3) * 8;
      gload_lds16(A + (size_t)(m0 + row) * sA + k0 + col, &Als[seg * 512]);
      gload_lds16(W1T + (size_t)(n0 + row) * FEAT + kOff + k0 + col, &Bls[seg * 512]);
    }
    __syncthreads();
    bf16x8 aF[4], bF[4];
#pragma unroll
    for (int mf = 0; mf < 4; ++mf)
      aF[mf] = *(const bf16x8*)&Als[((w >> 1) * 64 + mf * 16 + (lane & 15)) * 32 + (lane >> 4) * 8];
#pragma unroll
    for (int nf = 0; nf < 4; ++nf)
      bF[nf] = *(const bf16x8*)&Bls[((w & 1) * 64 + nf * 16 + (lane & 15)) * 32 + (lane >> 4) * 8];
#pragma unroll
    for (int mf = 0; mf < 4; ++mf)
#pragma unroll
      for (int nf = 0; nf < 4; ++nf)
        acc[mf][nf] = __builtin_amdgcn_mfma_f32_16x16x32_bf16(aF[mf], bF[nf], acc[mf][nf], 0, 0, 0);
  }
  int mq = (w >> 1) * 64, nq = (w & 1) * 64;
#pragma unroll
  for (int mf = 0; mf < 4; ++mf)
#pragma unroll
    for (int nf = 0; nf < 4; ++nf) {
      int n = n0 + nq + nf * 16 + (lane & 15);
      float bv = bias ? bias[n] : 0.f;
#pragma unroll
      for (int r = 0; r < 4; ++r) {
        int m = m0 + mq + mf * 16 + (lane >> 4) * 4 + r;
        if (m < Mrows) C[(size_t)m * HIDN + n] = acc[mf][nf][r] + bv;
      }
    }
}

// ---- PQ1 = P1 + Q[b] (in place on P1; Q already includes b1) ----
__global__ void k_pq(float* __restrict__ P1, const float* __restrict__ Q) {
  int r = blockIdx.x;
  const float* q = Q + (size_t)(r >> 5) * HIDN;
  float* p = P1 + (size_t)r * HIDN;
  for (int n = threadIdx.x; n < HIDN; n += 256) p[n] += q[n];
}

__global__ void k_zero(float* __restrict__ p, int n) {
  int i = blockIdx.x * 256 + threadIdx.x;
  if (i < n) p[i] = 0.f;
}

// ---- layer-2 GEMM fused with layer-3 partial, N=256 per block ----
// M-tile 128 x N-tile 256, acc[4][8] per wave (2 waves/SIMD). Same proven
// 2-barrier double-buffered staging + on-the-fly A-construct as before, but
// each A-construct/P-stage now feeds 32 MFMA (was 16) and total A-construct
// VALU work halves (3072 blocks vs 6144).
// PARTIAL=true: plain store to per-nc2 slice (6 slices); false: atomicAdd.
// LDS: B[2][16384] @0 | P2s[2][4096] @32768 | PQ1s[2][1024] @40960 = 43008
template <bool PARTIAL>
__global__ __launch_bounds__(256, 2)
void k_gemm2(const float* __restrict__ PQ1, const float* __restrict__ P2,
             const unsigned short* __restrict__ W2T,
             const float* __restrict__ b2, const float* __restrict__ W3,
             float* __restrict__ Lout) {
  __shared__ alignas(16) unsigned char LB[43008];
  int raw = blockIdx.x;
  int bx = (raw & 7) * 384 + (raw >> 3);   // XCD-chunked, bijective (3072 % 8 == 0)
  int mt = bx / 6, nc2 = bx - mt * 6;
  int m0 = mt * 128, n0 = nc2 * 256;
  int tid = threadIdx.x, lane = tid & 63, w = tid >> 6;
  int bG = m0 >> 10;
  int i0 = (m0 >> 5) & 31;
  int ks = lane >> 4;
  int r  = lane & 15;

  const int swcolB = ((lane & 3) ^ ((lane >> 3) & 3)) * 8;
  const int swcolP = (((lane >> 1) & 3) ^ ((lane >> 3) & 3)) * 8 + (lane & 1) * 4;

  auto STAGEB = [&](int kt, int buf) {
#pragma unroll
    for (int q = 0; q < 4; ++q) {
      int seg = w * 4 + q;
      int row = seg * 16 + (lane >> 2);
      gload_lds16(W2T + (size_t)(n0 + row) * HIDN + kt * 32 + swcolB,
                  LB + buf * 16384 + seg * 1024);
    }
  };
  auto STAGESRC = [&](int kt, int buf) {
    gload_lds16(P2 + (size_t)(bG * NPER + 8 * w + (lane >> 3)) * HIDN + kt * 32 + swcolP,
                LB + 32768 + buf * 4096 + w * 1024);
    if (w == 0)
      gload_lds16(PQ1 + (size_t)(bG * NPER + i0 + (lane >> 3)) * HIDN + kt * 32 + (lane & 7) * 4,
                  LB + 40960 + buf * 1024);
  };

  fv4 acc[4][8] = {};

  STAGEB(0, 0);
  STAGESRC(0, 0);
  __syncthreads();

  for (int kt = 0; kt < 92; ++kt) {
    int cur = kt & 1, nxt = cur ^ 1;
    if (kt < 91) { STAGEB(kt + 1, nxt); STAGESRC(kt + 1, nxt); }

    const unsigned char* Bb = LB + cur * 16384;
    const unsigned char* Pb = LB + 32768 + cur * 4096;
    const unsigned char* Qb = LB + 40960 + cur * 1024;

    int il0 = (w >> 1) * 2;
    int psw = (ks ^ (r & 3)) * 32;
    fv4 q0[2], q1[2], p0[2], p1[2];
#pragma unroll
    for (int h = 0; h < 2; ++h) {
      q0[h] = *(const fv4*)(Qb + il0 * 128 + ks * 32 + h * 16);
      q1[h] = *(const fv4*)(Qb + (il0 + 1) * 128 + ks * 32 + h * 16);
      p0[h] = *(const fv4*)(Pb + r * 128 + psw + h * 16);
      p1[h] = *(const fv4*)(Pb + (16 + r) * 128 + psw + h * 16);
    }
    bf16x8 bF[8];
#pragma unroll
    for (int nf = 0; nf < 8; ++nf) {
      int brow = (w & 1) * 128 + nf * 16 + r;
      int slot = ks ^ ((brow >> 1) & 3);
      bF[nf] = *(const bf16x8*)(Bb + brow * 64 + slot * 16);
    }

    bf16x8 aF[4];
#pragma unroll
    for (int mf = 0; mf < 4; ++mf) {
      fv4 s0 = (mf & 2 ? q1[0] : q0[0]) + (mf & 1 ? p1[0] : p0[0]);
      fv4 s1 = (mf & 2 ? q1[1] : q0[1]) + (mf & 1 ? p1[1] : p0[1]);
      uiv4 u;
      u[0] = cvt_pk_bf16(fmaxf(s0[0], 0.f), fmaxf(s0[1], 0.f));
      u[1] = cvt_pk_bf16(fmaxf(s0[2], 0.f), fmaxf(s0[3], 0.f));
      u[2] = cvt_pk_bf16(fmaxf(s1[0], 0.f), fmaxf(s1[1], 0.f));
      u[3] = cvt_pk_bf16(fmaxf(s1[2], 0.f), fmaxf(s1[3], 0.f));
      aF[mf] = __builtin_bit_cast(bf16x8, u);
    }

#pragma unroll
    for (int nf = 0; nf < 8; ++nf)
#pragma unroll
      for (int mf = 0; mf < 4; ++mf)
        acc[mf][nf] = __builtin_amdgcn_mfma_f32_16x16x32_bf16(aF[mf], bF[nf], acc[mf][nf], 0, 0, 0);
    __syncthreads();
  }

  // epilogue: h2 = relu(acc + b2); partial logits = h2 @ W3 chunk (128 n-cols
  // per wave); wave shfl reduce; cross-wave LDS reduce; store (or atomic).
  float* red = (float*)LB;
  int nq = (w & 1) * 128;
#pragma unroll
  for (int mf = 0; mf < 4; ++mf) {
    float s[4][NA];
#pragma unroll
    for (int rr = 0; rr < 4; ++rr)
#pragma unroll
      for (int a = 0; a < NA; ++a) s[rr][a] = 0.f;
#pragma unroll
    for (int nf = 0; nf < 8; ++nf) {
      int n = n0 + nq + nf * 16 + r;
      if (n < FEAT) {  // boundary multiple of 16 -> uniform per nf
        float bv = b2[n];
        float w3r[NA];
#pragma unroll
        for (int a = 0; a < NA; ++a) w3r[a] = W3[n * NA + a];
#pragma unroll
        for (int rr = 0; rr < 4; ++rr) {
          float h = fmaxf(acc[mf][nf][rr] + bv, 0.f);
#pragma unroll
          for (int a = 0; a < NA; ++a) s[rr][a] += h * w3r[a];
        }
      }
    }
#pragma unroll
    for (int off = 1; off < 16; off <<= 1)
#pragma unroll
      for (int rr = 0; rr < 4; ++rr)
#pragma unroll
        for (int a = 0; a < NA; ++a) s[rr][a] += __shfl_xor(s[rr][a], off, 64);
    int a = r;
    if (a < NA) {
#pragma unroll
      for (int rr = 0; rr < 4; ++rr)
        red[w * 704 + (mf * 16 + ks * 4 + rr) * NA + a] = s[rr][a];
    }
  }
  __syncthreads();
  for (int e = tid; e < 128 * NA; e += 256) {
    int row = e / NA, a = e - row * NA;
    int wr = row >> 6, rr = row & 63;
    float v = red[(wr * 2 + 0) * 704 + rr * NA + a] + red[(wr * 2 + 1) * 704 + rr * NA + a];
    if (PARTIAL)
      Lout[(size_t)nc2 * (MEDGE * NA) + (size_t)(m0 + row) * NA + a] = v;
    else
      atomicAdd(&Lout[(size_t)(m0 + row) * NA + a], v);
  }
}

// ---- symmetrize + b3, summing NS partial slices ----
template <int NS>
__global__ void k_sym(const float* __restrict__ LRp, const float* __restrict__ b3,
                      float* __restrict__ out) {
  int e = blockIdx.x * 256 + threadIdx.x;
  if (e >= MEDGE * NA) return;
  int m = e / NA, a = e - m * NA;
  int msw = (m & ~1023) | ((m & 31) << 5) | ((m >> 5) & 31);
  float s = 0.f;
#pragma unroll
  for (int t = 0; t < NS; ++t)
    s += LRp[(size_t)t * (MEDGE * NA) + e] + LRp[(size_t)t * (MEDGE * NA) + (size_t)msw * NA + a];
  out[e] = 0.5f * s + b3[a];
}

extern "C" void kernel_launch(void* const* d_in, const int* in_sizes, int n_in,
                              void* d_out, int out_size, void* d_ws, size_t ws_size,
                              hipStream_t stream) {
  const int*   idx      = (const int*)d_in[0];
  const int*   mlt      = (const int*)d_in[1];
  const float* z        = (const float*)d_in[2];
  const float* id_emb   = (const float*)d_in[3];
  const float* mult_emb = (const float*)d_in[4];
  const float* W1       = (const float*)d_in[5];
  const float* b1       = (const float*)d_in[6];
  const float* W2       = (const float*)d_in[7];
  const float* b2       = (const float*)d_in[8];
  const float* W3       = (const float*)d_in[9];
  const float* b3       = (const float*)d_in[10];
  float* out = (float*)d_out;

  uint8_t* ws = (uint8_t*)d_ws;
  size_t o = 0;
  auto alloc = [&](size_t bytes) { size_t r = o; o += (bytes + 255) & ~(size_t)255; return r; };
  size_t oW1T = alloc((size_t)HIDN * FEAT * 2);       // bf16 [2944][1472]
  size_t oW2T = alloc((size_t)FEATP * HIDN * 2);      // bf16 [1536][2944]
  size_t oXB  = alloc((size_t)NROWS * DNODE * 2);     // bf16 [2048][320]
  size_t oZA  = alloc((size_t)128 * 832 * 2);         // bf16 [128][832]
  size_t oAG  = alloc((size_t)NBG * DNODE * 4);       // f32  [64][320]
  size_t oP1  = alloc((size_t)NROWS * HIDN * 4);      // f32  [2048][2944]
  size_t oP2  = alloc((size_t)NROWS * HIDN * 4);
  size_t oQ   = alloc((size_t)NBG * HIDN * 4);
  size_t oLRp = alloc((size_t)6 * MEDGE * NA * 4);    // 6 partial slices (or slice 0 for atomics)
  size_t needPartial = o;                              // ~85.6 MB
  size_t needAtomic  = oLRp + (((size_t)MEDGE * NA * 4 + 255) & ~(size_t)255);  // ~71.2 MB (known good)
  if (ws_size < needAtomic) return;  // insufficient workspace
  bool partial = (ws_size >= needPartial);

  unsigned short* W1T = (unsigned short*)(ws + oW1T);
  unsigned short* W2T = (unsigned short*)(ws + oW2T);
  unsigned short* xb  = (unsigned short*)(ws + oXB);
  unsigned short* za  = (unsigned short*)(ws + oZA);
  float* agg = (float*)(ws + oAG);
  float* P1  = (float*)(ws + oP1);
  float* P2  = (float*)(ws + oP2);
  float* Qm  = (float*)(ws + oQ);
  float* LRp = (float*)(ws + oLRp);

  k_transpose_bf16<<<dim3(FEAT / 64, HIDN / 64), 256, 0, stream>>>(W1, W1T, FEAT, HIDN, HIDN);
  k_transpose_bf16<<<dim3(HIDN / 64, FEATP / 64), 256, 0, stream>>>(W2, W2T, HIDN, FEAT, FEATP);
  k_embed<<<NROWS, 256, 0, stream>>>(idx, mlt, id_emb, mult_emb, xb);
  k_agg<<<NBG, 256, 0, stream>>>(xb, agg);
  k_za<<<128, 256, 0, stream>>>(z, agg, za);
  k_gemm1<<<16 * 23, 256, 0, stream>>>(xb, DNODE, NROWS, W1T, 0, 10, P1, nullptr);
  k_gemm1<<<16 * 23, 256, 0, stream>>>(xb, DNODE, NROWS, W1T, 320, 10, P2, nullptr);
  k_gemm1<<<1 * 23, 256, 0, stream>>>(za, 832, NBG, W1T, 640, 26, Qm, b1);
  k_pq<<<NROWS, 256, 0, stream>>>(P1, Qm);

  if (partial) {
    k_gemm2<true><<<512 * 6, 256, 0, stream>>>(P1, P2, W2T, b2, W3, LRp);
    k_sym<6><<<(MEDGE * NA + 255) / 256, 256, 0, stream>>>(LRp, b3, out);
  } else {
    k_zero<<<(MEDGE * NA + 255) / 256, 256, 0, stream>>>(LRp, MEDGE * NA);
    k_gemm2<false><<<512 * 6, 256, 0, stream>>>(P1, P2, W2T, b2, W3, LRp);
    k_sym<1><<<(MEDGE * NA + 255) / 256, 256, 0, stream>>>(LRp, b3, out);
  }
}